// Round 4
// baseline (96.455 us; speedup 1.0000x reference)
//
#include <hip/hip_runtime.h>

// TileRenderer: out[p,b,y,x] = sum_s bilinear_sample(sources[p,s,b], affine(locs[p,s]))
// n_ptiles=1024, max_src=4, n_bands=5, ptile_slen=52.
//
// Affine (exact): l = (loc*(4/52) + 24/52 - 0.5)*2
//   ix = x*(25.5/26) + (1-l1)*25.5 - 25.5^2/26   (grid[...,0] uses swapped l)
//   iy = y*(25.5/26) + (1-l0)*25.5 - 25.5^2/26
// For locs in [0,1]: ix0 = floor(ix) in [-2,52], reads cols [-2,53]; same for y.
// Zero-padded LDS tile (rows -2..53, cols -4..55, stride 60) makes every
// out-of-range corner read an actual 0.0f => reference's zeros-padding mask
// semantics with NO masks/clamps in the inner loop.
constexpr int NP = 1024;
constexpr int MS = 4;
constexpr int NB = 5;
constexpr int SL = 52;
constexpr int SS = SL * SL;     // 2704
constexpr int NTHR = 256;
constexpr int NJ = 11;          // ceil(SS/NTHR)
constexpr int TAIL = SS - (NJ - 1) * NTHR;  // 144
constexpr int PST = 60;         // padded row stride (floats); 240B, 16B-mult
constexpr int PROWS = 56;       // rows -2..53
constexpr int PX = 4;           // col pad: interior col0 at 4 (16B alignment)
constexpr int PY = 2;
constexpr int BUFF = PROWS * PST;   // 3360 floats = 13440 B per buffer
constexpr int NCH = SS / 4;     // 676 float4 chunks per slice (13/row exact)

__global__ __launch_bounds__(NTHR) void tile_render_kernel(
    const float* __restrict__ locs,
    const float* __restrict__ sources,
    float* __restrict__ out)
{
    __shared__ __align__(16) float smem[2 * BUFF];  // 26880 B -> 6 blocks/CU

    const int blk = blockIdx.x;
    const int p = blk / NB;
    const int b = blk - p * NB;
    const int tid = threadIdx.x;

    // Zero both padded buffers (pads must read 0; interior overwritten below).
    for (int i = 4 * tid; i < 2 * BUFF; i += 4 * NTHR)
        *reinterpret_cast<float4*>(smem + i) = make_float4(0.f, 0.f, 0.f, 0.f);

    const float A = 25.5f / 26.0f;
    float bx[MS], by[MS];
    #pragma unroll
    for (int s = 0; s < MS; ++s) {
        float loc0 = locs[(p * MS + s) * 2 + 0];
        float loc1 = locs[(p * MS + s) * 2 + 1];
        float l0 = (loc0 * (4.0f / 52.0f) + (24.0f / 52.0f) - 0.5f) * 2.0f;
        float l1 = (loc1 * (4.0f / 52.0f) + (24.0f / 52.0f) - 0.5f) * 2.0f;
        bx[s] = (1.0f - l1) * 25.5f - 25.5f * 25.5f / 26.0f;
        by[s] = (1.0f - l0) * 25.5f - 25.5f * 25.5f / 26.0f;
    }

    // Per-thread output pixel coords (j=NJ-1 dummy-safe for tid>=TAIL).
    float fx[NJ], fy[NJ];
    #pragma unroll
    for (int j = 0; j < NJ; ++j) {
        int pix = tid + j * NTHR;
        if (pix >= SS) pix = 0;
        int y = pix / SL;
        fx[j] = (float)(pix - y * SL);
        fy[j] = (float)y;
    }

    // Staging chunk -> padded LDS offset. Chunk c: row c/13, col (c%13)*4.
    // LDS float offset (row+PY)*PST + PX + col  ->  16B aligned.
    int woff[3];
    bool has2;
    {
        #pragma unroll
        for (int u = 0; u < 3; ++u) {
            int c = tid + u * NTHR;
            int cc = (c < NCH) ? c : 0;
            int r = cc / 13;
            woff[u] = (r + PY) * PST + PX + (cc - r * 13) * 4;
        }
        has2 = (tid < NCH - 2 * NTHR);  // 164 threads carry a 3rd chunk
    }

    const float* gsrc = sources + ((size_t)p * MS * NB + b) * SS;

    float4 ra, rb, rc;
    auto issue = [&](int s) {
        const float* g = gsrc + (size_t)s * (NB * SS);
        ra = *reinterpret_cast<const float4*>(g + 4 * tid);
        rb = *reinterpret_cast<const float4*>(g + 4 * (tid + NTHR));
        if (has2) rc = *reinterpret_cast<const float4*>(g + 4 * (tid + 2 * NTHR));
    };
    auto write_lds = [&](float* buf) {
        *reinterpret_cast<float4*>(buf + woff[0]) = ra;
        *reinterpret_cast<float4*>(buf + woff[1]) = rb;
        if (has2) *reinterpret_cast<float4*>(buf + woff[2]) = rc;
    };

    float acc[NJ];
    #pragma unroll
    for (int j = 0; j < NJ; ++j) acc[j] = 0.0f;

    issue(0);
    __syncthreads();        // zero-init complete everywhere
    write_lds(smem);        // (compiler inserts vmcnt wait here)
    __syncthreads();        // buf0 ready

    const float* const adj0 = smem + PY * PST + PX;

    #pragma unroll
    for (int s = 0; s < MS; ++s) {
        if (s < MS - 1) issue(s + 1);   // loads in flight across compute

        const float* adj = adj0 + ((s & 1) ? BUFF : 0);
        const float bxs = bx[s], bys = by[s];
        #pragma unroll
        for (int j = 0; j < NJ; ++j) {
            float ix = fmaf(fx[j], A, bxs);
            float iy = fmaf(fy[j], A, bys);
            float ixf = floorf(ix);
            float iyf = floorf(iy);
            float wx = ix - ixf;
            float wy = iy - iyf;
            int xi = (int)ixf;
            int yi = (int)iyf;
            const float* q = adj + yi * PST + xi;
            float v00 = q[0], v01 = q[1];          // ds_read2_b32 off 0,1
            float v10 = q[PST], v11 = q[PST + 1];  // ds_read2_b32 off 60,61
            float h0 = fmaf(wx, v01 - v00, v00);
            float h1 = fmaf(wx, v11 - v10, v10);
            acc[j] += fmaf(wy, h1 - h0, h0);
        }

        if (s < MS - 1) {
            write_lds(smem + (((s + 1) & 1) ? BUFF : 0));  // vmcnt wait here
            __syncthreads();    // next buffer ready; cur reads all done
        }
    }

    float* outp = out + ((size_t)p * NB + b) * SS;
    #pragma unroll
    for (int j = 0; j < NJ; ++j) {
        int pix = tid + j * NTHR;
        if (j < NJ - 1 || tid < TAIL) outp[pix] = acc[j];
    }
}

extern "C" void kernel_launch(void* const* d_in, const int* in_sizes, int n_in,
                              void* d_out, int out_size, void* d_ws, size_t ws_size,
                              hipStream_t stream) {
    const float* locs = (const float*)d_in[0];
    const float* sources = (const float*)d_in[1];
    float* out = (float*)d_out;
    dim3 grid(NP * NB);
    dim3 block(NTHR);
    hipLaunchKernelGGL(tile_render_kernel, grid, block, 0, stream,
                       locs, sources, out);
}

// Round 5
// 87.214 us; speedup vs baseline: 1.1060x; 1.1060x over previous
//
#include <hip/hip_runtime.h>

// TileRenderer: out[p,b,y,x] = sum_s bilinear_sample(sources[p,s,b], affine(locs[p,s]))
// n_ptiles=1024, max_src=4, n_bands=5, ptile_slen=52.
//
// Affine (exact): l = (loc*(4/52) + 24/52 - 0.5)*2
//   ix = x*(25.5/26) + (1-l1)*25.5 - 25.5^2/26   (grid[...,0] uses swapped l)
//   iy = y*(25.5/26) + (1-l0)*25.5 - 25.5^2/26
//
// No-LDS design: per-block working set is 4 slices x 10.8 KB with only ~4x
// reuse per source pixel -> L1 (32 KiB) serves the corner taps. No barriers,
// no staging, scalar accumulator, high occupancy. Each slice is read by
// exactly one block and is 64B-aligned (10816 B = 169 lines), so HBM fetch
// stays at the ideal 221.5 MB.
constexpr int NP = 1024;
constexpr int MS = 4;
constexpr int NB = 5;
constexpr int SL = 52;
constexpr int SS = SL * SL;   // 2704
constexpr int NTHR = 256;

__global__ __launch_bounds__(NTHR) void tile_render_kernel(
    const float* __restrict__ locs,
    const float* __restrict__ sources,
    float* __restrict__ out)
{
    const int blk = blockIdx.x;
    const int p = blk / NB;
    const int b = blk - p * NB;
    const int tid = threadIdx.x;

    const float A = 25.5f / 26.0f;
    float bx[MS], by[MS];
    #pragma unroll
    for (int s = 0; s < MS; ++s) {
        float loc0 = locs[(p * MS + s) * 2 + 0];
        float loc1 = locs[(p * MS + s) * 2 + 1];
        float l0 = (loc0 * (4.0f / 52.0f) + (24.0f / 52.0f) - 0.5f) * 2.0f;
        float l1 = (loc1 * (4.0f / 52.0f) + (24.0f / 52.0f) - 0.5f) * 2.0f;
        bx[s] = (1.0f - l1) * 25.5f - 25.5f * 25.5f / 26.0f;
        by[s] = (1.0f - l0) * 25.5f - 25.5f * 25.5f / 26.0f;
    }

    const float* img0 = sources + ((size_t)p * MS * NB + b) * SS;
    float* outp = out + ((size_t)p * NB + b) * SS;

    for (int pix = tid; pix < SS; pix += NTHR) {
        int y = pix / SL;
        int x = pix - y * SL;
        float xf = (float)x, yf = (float)y;
        float acc = 0.0f;
        #pragma unroll
        for (int s = 0; s < MS; ++s) {
            const float* img = img0 + s * (NB * SS);
            float ix = fmaf(xf, A, bx[s]);
            float iy = fmaf(yf, A, by[s]);
            float ixf = floorf(ix);
            float iyf = floorf(iy);
            float wx1 = ix - ixf;
            float wy1 = iy - iyf;
            float wx0 = 1.0f - wx1;
            float wy0 = 1.0f - wy1;
            int xi = (int)ixf;
            int yi = (int)iyf;
            // zeros padding folded into 1-D weights; taps clamped in-bounds
            float wxa = ((unsigned)xi        <= 51u) ? wx0 : 0.0f;
            float wxb = ((unsigned)(xi + 1)  <= 51u) ? wx1 : 0.0f;
            float wya = ((unsigned)yi        <= 51u) ? wy0 : 0.0f;
            float wyb = ((unsigned)(yi + 1)  <= 51u) ? wy1 : 0.0f;
            int x0 = min(max(xi, 0), SL - 1);          // v_med3_i32
            int x1 = min(max(xi + 1, 0), SL - 1);
            int r0 = min(max(yi, 0), SL - 1) * SL;
            int r1 = min(max(yi + 1, 0), SL - 1) * SL;
            float v00 = img[r0 + x0], v01 = img[r0 + x1];
            float v10 = img[r1 + x0], v11 = img[r1 + x1];
            float h0 = fmaf(v01, wxb, v00 * wxa);
            float h1 = fmaf(v11, wxb, v10 * wxa);
            acc = fmaf(h0, wya, acc);
            acc = fmaf(h1, wyb, acc);
        }
        outp[pix] = acc;
    }
}

extern "C" void kernel_launch(void* const* d_in, const int* in_sizes, int n_in,
                              void* d_out, int out_size, void* d_ws, size_t ws_size,
                              hipStream_t stream) {
    const float* locs = (const float*)d_in[0];
    const float* sources = (const float*)d_in[1];
    float* out = (float*)d_out;
    dim3 grid(NP * NB);
    dim3 block(NTHR);
    hipLaunchKernelGGL(tile_render_kernel, grid, block, 0, stream,
                       locs, sources, out);
}

// Round 6
// 48.892 us; speedup vs baseline: 1.9728x; 1.7838x over previous
//
#include <hip/hip_runtime.h>

// TileRenderer: out[p,b,y,x] = sum_s bilinear_sample(sources[p,s,b], affine(locs[p,s]))
// n_ptiles=1024, max_src=4, n_bands=5, ptile_slen=52.
//
// Affine (exact): l = (loc*(4/52) + 24/52 - 0.5)*2
//   ix = x*(25.5/26) + (1-l1)*25.5 - 25.5^2/26   (grid[...,0] uses swapped l)
//   iy = y*(25.5/26) + (1-l0)*25.5 - 25.5^2/26
// For locs in [0,1]: floor(ix), floor(iy) in [-2,52].
//
// Structure = round-3 (proven): global_load_lds staging, double-buffer,
// one barrier per source. New: LDS buffer is zero-padded in Y ONLY
// (rows -2..53) — interior stays one linear 2704-float block (16B-aligned
// at float offset 108), so global_load_lds still works, while
//   * y needs no mask and no clamp (pad rows are real zeros),
//   * row1 = row0 + 52 is a STATIC ds offset (ds_read2_b32 0/52 and 1/53),
//   * only x keeps mask (2 cmp + 2 sel) + one med3 clamp.
// Front/tail 4-float pads keep x=-1/52 reads in-bounds (garbage, weight 0).
constexpr int NP = 1024;
constexpr int MS = 4;
constexpr int NB = 5;
constexpr int SL = 52;
constexpr int SS = SL * SL;     // 2704
constexpr int NTHR = 256;
constexpr int NJ = 11;          // ceil(SS/256)
constexpr int TAIL = SS - (NJ - 1) * NTHR;  // 144
constexpr int NCH = SS / 4;     // 676 float4 chunks
constexpr int FPAD = 4;         // front/tail pad (floats)
constexpr int PY = 2;           // zero pad rows above/below
constexpr int BUFF = FPAD + (SL + 2 * PY) * SL + FPAD;  // 4+2912+4 = 2920
constexpr int INT0 = FPAD + PY * SL;  // 108: interior (row0,col0); 432B, 16B-mult

__device__ __forceinline__ void gload_lds16(const float* g, float* l) {
    __builtin_amdgcn_global_load_lds(
        (const __attribute__((address_space(1))) void*)g,
        (__attribute__((address_space(3))) void*)l,
        16, 0, 0);
}

__global__ __launch_bounds__(NTHR) void tile_render_kernel(
    const float* __restrict__ locs,
    const float* __restrict__ sources,
    float* __restrict__ out)
{
    __shared__ __align__(16) float smem[2 * BUFF];  // 23360 B -> ~7 blocks/CU

    const int blk = blockIdx.x;
    const int p = blk / NB;
    const int b = blk - p * NB;
    const int tid = threadIdx.x;

    // Zero both buffers (pads must be genuine zeros; interior re-staged).
    for (int i = 4 * tid; i < 2 * BUFF; i += 4 * NTHR)
        *reinterpret_cast<float4*>(smem + i) = make_float4(0.f, 0.f, 0.f, 0.f);

    const float A = 25.5f / 26.0f;
    float bx[MS], by[MS];
    #pragma unroll
    for (int s = 0; s < MS; ++s) {
        float loc0 = locs[(p * MS + s) * 2 + 0];
        float loc1 = locs[(p * MS + s) * 2 + 1];
        float l0 = (loc0 * (4.0f / 52.0f) + (24.0f / 52.0f) - 0.5f) * 2.0f;
        float l1 = (loc1 * (4.0f / 52.0f) + (24.0f / 52.0f) - 0.5f) * 2.0f;
        bx[s] = (1.0f - l1) * 25.5f - 25.5f * 25.5f / 26.0f;
        by[s] = (1.0f - l0) * 25.5f - 25.5f * 25.5f / 26.0f;
    }

    // Hoisted per-thread pixel coords (j = NJ-1 dummy-safe for tid >= TAIL).
    float fx[NJ], fy[NJ];
    #pragma unroll
    for (int j = 0; j < NJ; ++j) {
        int pix = tid + j * NTHR;
        if (pix >= SS) pix = 0;
        int y = pix / SL;
        fx[j] = (float)(pix - y * SL);
        fy[j] = (float)y;
    }

    const float* gsrc = sources + ((size_t)p * MS * NB + b) * SS;
    auto stage = [&](float* buf, int s) {
        const float* g = gsrc + (size_t)s * (NB * SS);
        float* dst = buf + INT0;
        gload_lds16(g + 4 * tid,          dst + 4 * tid);
        gload_lds16(g + 4 * (tid + NTHR), dst + 4 * (tid + NTHR));
        if (tid < NCH - 2 * NTHR)
            gload_lds16(g + 4 * (tid + 2 * NTHR), dst + 4 * (tid + 2 * NTHR));
    };

    float acc[NJ];
    #pragma unroll
    for (int j = 0; j < NJ; ++j) acc[j] = 0.0f;

    __syncthreads();        // zero-init visible before staging overwrites
    stage(smem, 0);

    #pragma unroll
    for (int s = 0; s < MS; ++s) {
        // Barrier drains vmcnt: buffer for s is ready; all reads of the
        // other buffer (s-1's compute) are also done, so restaging is safe.
        __syncthreads();
        if (s < MS - 1) stage(smem + ((s + 1) & 1) * BUFF, s + 1);

        const float* cur = smem + (s & 1) * BUFF;
        const float bxs = bx[s], bys = by[s];
        #pragma unroll
        for (int j = 0; j < NJ; ++j) {
            float ix = fmaf(fx[j], A, bxs);
            float iy = fmaf(fy[j], A, bys);
            float ixf = floorf(ix);
            float iyf = floorf(iy);
            float wx = ix - ixf;
            float wy = iy - iyf;
            int xi = (int)ixf;
            int yi = (int)iyf;
            float wx0 = 1.0f - wx;
            // x: zeros-padding folded into weights; tap base clamped so the
            // {xc, xc+1} pair covers every valid corner, OOB half masked.
            float wxa = ((unsigned)xi       <= 51u) ? wx0 : 0.0f;
            float wxb = ((unsigned)(xi + 1) <= 51u) ? wx  : 0.0f;
            int xc = min(max(xi, -1), SL - 1);
            // y: no mask, no clamp — pad rows are zeros; r1 = r0 + 52 static.
            const float* q = cur + (yi * SL + (xc + INT0));
            float v00 = q[0],  v01 = q[1];        // ds_read2_b32
            float v10 = q[SL], v11 = q[SL + 1];   // ds_read2_b32
            float h0 = fmaf(v01, wxb, v00 * wxa);
            float h1 = fmaf(v11, wxb, v10 * wxa);
            acc[j] = fmaf(wy, h1 - h0, h0 + acc[j]);
        }
    }

    float* outp = out + ((size_t)p * NB + b) * SS;
    #pragma unroll
    for (int j = 0; j < NJ; ++j) {
        int pix = tid + j * NTHR;
        if (j < NJ - 1 || tid < TAIL) outp[pix] = acc[j];
    }
}

extern "C" void kernel_launch(void* const* d_in, const int* in_sizes, int n_in,
                              void* d_out, int out_size, void* d_ws, size_t ws_size,
                              hipStream_t stream) {
    const float* locs = (const float*)d_in[0];
    const float* sources = (const float*)d_in[1];
    float* out = (float*)d_out;
    dim3 grid(NP * NB);
    dim3 block(NTHR);
    hipLaunchKernelGGL(tile_render_kernel, grid, block, 0, stream,
                       locs, sources, out);
}